// Round 9
// baseline (300.097 us; speedup 1.0000x reference)
//
#include <hip/hip_runtime.h>
#include <hip/hip_cooperative_groups.h>
#include <math.h>

namespace cg = cooperative_groups;

#define AFWD 0.999f
#define ONE_MINUS_A (1.0f - 0.999f)
#define KCOEF (0.999f * (1.0f - 0.999f))
#define EPSV 1e-5f

typedef float floatx4 __attribute__((ext_vector_type(4)));

// ===========================================================================
// Fused cooperative kernel (1 dispatch). C=128 -> 512 blocks, co-resident
// even at 2 blocks/CU. B-phase unrolls capped at 4 (R8's unroll-16 blew the
// VGPR budget -> coop launch rejected -> zeros).
// ===========================================================================
__global__ __launch_bounds__(256) void
fused_cn3(const float* __restrict__ x, const float* __restrict__ m,
          const float* __restrict__ var, float* __restrict__ out,
          float* __restrict__ Bmu, float* __restrict__ See,
          float* __restrict__ Te, float* __restrict__ Ms,
          float* __restrict__ Vs, float* __restrict__ Bsup,
          float* __restrict__ Ssup, float* __restrict__ Tsup,
          float* __restrict__ Mg, float* __restrict__ Vg,
          int L, int L4, int C, int CH, int SUB, int GS,
          float A, float c_eg, float Sgg, float G,
          float Asup, float c_sup, float Sggsup) {
  cg::grid_group grid = cg::this_grid();

  int idx  = blockIdx.x * blockDim.x + threadIdx.x;
  int col4 = idx % L4;
  int c    = idx / L4;
  const floatx4* xv = (const floatx4*)x;
  int base = c * CH * L4 + col4;
  int o    = c * L4 + col4;

  // ---------------- phase A: chunk summaries (M=0 start) ----------------
  {
    float mu[4] = {0.f, 0.f, 0.f, 0.f};
    float s[4]  = {0.f, 0.f, 0.f, 0.f};
    float t[4]  = {0.f, 0.f, 0.f, 0.f};
#pragma unroll 1
    for (int i = 0; i < CH; i += 4) {
      floatx4 v0 = xv[base + (i + 0) * L4];
      floatx4 v1 = xv[base + (i + 1) * L4];
      floatx4 v2 = xv[base + (i + 2) * L4];
      floatx4 v3 = xv[base + (i + 3) * L4];
#pragma unroll
      for (int k = 0; k < 4; ++k) {
        float e = v0[k] - mu[k];
        s[k] = fmaf(AFWD, s[k], e * e); t[k] += e;
        mu[k] = fmaf(ONE_MINUS_A, e, mu[k]);
      }
#pragma unroll
      for (int k = 0; k < 4; ++k) {
        float e = v1[k] - mu[k];
        s[k] = fmaf(AFWD, s[k], e * e); t[k] += e;
        mu[k] = fmaf(ONE_MINUS_A, e, mu[k]);
      }
#pragma unroll
      for (int k = 0; k < 4; ++k) {
        float e = v2[k] - mu[k];
        s[k] = fmaf(AFWD, s[k], e * e); t[k] += e;
        mu[k] = fmaf(ONE_MINUS_A, e, mu[k]);
      }
#pragma unroll
      for (int k = 0; k < 4; ++k) {
        float e = v3[k] - mu[k];
        s[k] = fmaf(AFWD, s[k], e * e); t[k] += e;
        mu[k] = fmaf(ONE_MINUS_A, e, mu[k]);
      }
    }
    floatx4 om = {mu[0], mu[1], mu[2], mu[3]};
    floatx4 os = {s[0], s[1], s[2], s[3]};
    floatx4 ot = {t[0], t[1], t[2], t[3]};
    ((floatx4*)Bmu)[o] = om;
    ((floatx4*)See)[o] = os;
    ((floatx4*)Te)[o]  = ot;
  }

  grid.sync();

  // ---------------- phase B1: super-chunk summaries ----------------
  if (idx < L * GS) {
    int l = idx % L;
    int g = idx / L;
    int b1 = g * SUB * L + l;
    float B = 0.f, T = 0.f, S = 0.f;
#pragma unroll 4
    for (int k = 0; k < SUB; ++k) {
      int oo = b1 + k * L;
      float b2 = Bmu[oo];
      float s2 = See[oo];
      float t2 = Te[oo];
      S = fmaf(A, S, fmaf(Sgg * B, B, fmaf(-2.0f * c_eg * B, t2, s2)));
      T = fmaf(-G, B, T + t2);
      B = fmaf(A, B, b2);
    }
    int oo = g * L + l;
    Bsup[oo] = B;
    Ssup[oo] = S;
    Tsup[oo] = T;
  }

  grid.sync();

  // ---------------- phase B2: walk super-chunks with (M0,V0) ----------------
  if (idx < L) {
    int l = idx;
    float M = m[l];
    float V = var[l];
#pragma unroll 4
    for (int g = 0; g < GS; ++g) {
      int oo = g * L + l;
      Mg[oo] = M;
      Vg[oo] = V;
      float b = Bsup[oo];
      float s = Ssup[oo];
      float t = Tsup[oo];
      float sum = fmaf(M * M, Sggsup, fmaf(-2.0f * c_sup * M, t, s));
      V = fmaf(Asup, V, KCOEF * sum);
      M = fmaf(Asup, M, b);
    }
  }

  grid.sync();

  // ---------------- phase B3: emit chunk-start states ----------------
  if (idx < L * GS) {
    int l = idx % L;
    int g = idx / L;
    int b3 = g * SUB * L + l;
    float M = Mg[g * L + l];
    float V = Vg[g * L + l];
#pragma unroll 4
    for (int k = 0; k < SUB; ++k) {
      int oo = b3 + k * L;
      Ms[oo] = M;
      Vs[oo] = V;
      float b = Bmu[oo];
      float s = See[oo];
      float t = Te[oo];
      float sum = fmaf(M * M, Sgg, fmaf(-2.0f * c_eg * M, t, s));
      V = fmaf(A, V, KCOEF * sum);
      M = fmaf(A, M, b);
    }
  }

  grid.sync();

  // ---------------- phase C: exact replay + output ----------------
  {
    floatx4* ov = (floatx4*)out;
    floatx4 m4 = ((const floatx4*)Ms)[o];
    floatx4 v4 = ((const floatx4*)Vs)[o];
    float mu[4] = {m4[0], m4[1], m4[2], m4[3]};
    float vv[4] = {v4[0], v4[1], v4[2], v4[3]};
#pragma unroll 1
    for (int i = 0; i < CH; i += 4) {
      floatx4 v0 = xv[base + (i + 0) * L4];
      floatx4 v1 = xv[base + (i + 1) * L4];
      floatx4 v2 = xv[base + (i + 2) * L4];
      floatx4 v3 = xv[base + (i + 3) * L4];
      floatx4 o0, o1, o2, o3;
#pragma unroll
      for (int k = 0; k < 4; ++k) {
        float d = v0[k] - mu[k];
        o0[k] = d * rsqrtf(vv[k] + EPSV);
        vv[k] = fmaf(AFWD, vv[k], KCOEF * (d * d));
        mu[k] = fmaf(ONE_MINUS_A, d, mu[k]);
      }
#pragma unroll
      for (int k = 0; k < 4; ++k) {
        float d = v1[k] - mu[k];
        o1[k] = d * rsqrtf(vv[k] + EPSV);
        vv[k] = fmaf(AFWD, vv[k], KCOEF * (d * d));
        mu[k] = fmaf(ONE_MINUS_A, d, mu[k]);
      }
#pragma unroll
      for (int k = 0; k < 4; ++k) {
        float d = v2[k] - mu[k];
        o2[k] = d * rsqrtf(vv[k] + EPSV);
        vv[k] = fmaf(AFWD, vv[k], KCOEF * (d * d));
        mu[k] = fmaf(ONE_MINUS_A, d, mu[k]);
      }
#pragma unroll
      for (int k = 0; k < 4; ++k) {
        float d = v3[k] - mu[k];
        o3[k] = d * rsqrtf(vv[k] + EPSV);
        vv[k] = fmaf(AFWD, vv[k], KCOEF * (d * d));
        mu[k] = fmaf(ONE_MINUS_A, d, mu[k]);
      }
      __builtin_nontemporal_store(o0, &ov[base + (i + 0) * L4]);
      __builtin_nontemporal_store(o1, &ov[base + (i + 1) * L4]);
      __builtin_nontemporal_store(o2, &ov[base + (i + 2) * L4]);
      __builtin_nontemporal_store(o3, &ov[base + (i + 3) * L4]);
    }
  }
}

// ===========================================================================
// Fallback separate kernels (proven R6/R7 path, 84-85 us).
// ===========================================================================
__global__ __launch_bounds__(256) void
passA(const float* __restrict__ x, float* __restrict__ Bmu,
      float* __restrict__ See, float* __restrict__ Te, int L4, int CH) {
  int idx  = blockIdx.x * blockDim.x + threadIdx.x;
  int col4 = idx % L4;
  int c    = idx / L4;
  const floatx4* xv = (const floatx4*)x;
  int base = c * CH * L4 + col4;

  float mu[4] = {0.f, 0.f, 0.f, 0.f};
  float s[4]  = {0.f, 0.f, 0.f, 0.f};
  float t[4]  = {0.f, 0.f, 0.f, 0.f};
#pragma unroll 4
  for (int i = 0; i < CH; ++i) {
    floatx4 v = xv[base + i * L4];
#pragma unroll
    for (int k = 0; k < 4; ++k) {
      float e = v[k] - mu[k];
      s[k] = fmaf(AFWD, s[k], e * e);
      t[k] += e;
      mu[k] = fmaf(ONE_MINUS_A, e, mu[k]);
    }
  }
  int o = c * L4 + col4;
  floatx4 om = {mu[0], mu[1], mu[2], mu[3]};
  floatx4 os = {s[0], s[1], s[2], s[3]};
  floatx4 ot = {t[0], t[1], t[2], t[3]};
  ((floatx4*)Bmu)[o] = om;
  ((floatx4*)See)[o] = os;
  ((floatx4*)Te)[o]  = ot;
}

__global__ __launch_bounds__(256) void
passB1(const float* __restrict__ Bmu, const float* __restrict__ See,
       const float* __restrict__ Te, float* __restrict__ Bsup,
       float* __restrict__ Ssup, float* __restrict__ Tsup, int L, int SUB,
       float A, float c_eg, float Sgg, float G) {
  int idx = blockIdx.x * blockDim.x + threadIdx.x;
  int l   = idx % L;
  int g   = idx / L;
  int base = g * SUB * L + l;
  float B = 0.f, T = 0.f, S = 0.f;
#pragma unroll 4
  for (int k = 0; k < SUB; ++k) {
    int o = base + k * L;
    float b2 = Bmu[o];
    float s2 = See[o];
    float t2 = Te[o];
    S = fmaf(A, S, fmaf(Sgg * B, B, fmaf(-2.0f * c_eg * B, t2, s2)));
    T = fmaf(-G, B, T + t2);
    B = fmaf(A, B, b2);
  }
  int o = g * L + l;
  Bsup[o] = B;
  Ssup[o] = S;
  Tsup[o] = T;
}

__global__ __launch_bounds__(256) void
passB2(const float* __restrict__ m, const float* __restrict__ var,
       const float* __restrict__ Bsup, const float* __restrict__ Ssup,
       const float* __restrict__ Tsup, float* __restrict__ Mg,
       float* __restrict__ Vg, int L, int GS, float Asup, float c_sup,
       float Sggsup) {
  int l = blockIdx.x * blockDim.x + threadIdx.x;
  float M = m[l];
  float V = var[l];
#pragma unroll 4
  for (int g = 0; g < GS; ++g) {
    int o = g * L + l;
    Mg[o] = M;
    Vg[o] = V;
    float b = Bsup[o];
    float s = Ssup[o];
    float t = Tsup[o];
    float sum = fmaf(M * M, Sggsup, fmaf(-2.0f * c_sup * M, t, s));
    V = fmaf(Asup, V, KCOEF * sum);
    M = fmaf(Asup, M, b);
  }
}

__global__ __launch_bounds__(256) void
passB3(const float* __restrict__ Bmu, const float* __restrict__ See,
       const float* __restrict__ Te, const float* __restrict__ Mg,
       const float* __restrict__ Vg, float* __restrict__ Ms,
       float* __restrict__ Vs, int L, int SUB, float A, float c_eg,
       float Sgg) {
  int idx = blockIdx.x * blockDim.x + threadIdx.x;
  int l   = idx % L;
  int g   = idx / L;
  int base = g * SUB * L + l;
  float M = Mg[g * L + l];
  float V = Vg[g * L + l];
#pragma unroll 4
  for (int k = 0; k < SUB; ++k) {
    int o = base + k * L;
    Ms[o] = M;
    Vs[o] = V;
    float b = Bmu[o];
    float s = See[o];
    float t = Te[o];
    float sum = fmaf(M * M, Sgg, fmaf(-2.0f * c_eg * M, t, s));
    V = fmaf(A, V, KCOEF * sum);
    M = fmaf(A, M, b);
  }
}

__global__ __launch_bounds__(256) void
passC(const float* __restrict__ x, const float* __restrict__ Ms,
      const float* __restrict__ Vs, float* __restrict__ out, int L4, int CH) {
  int idx  = blockIdx.x * blockDim.x + threadIdx.x;
  int col4 = idx % L4;
  int c    = idx / L4;
  const floatx4* xv = (const floatx4*)x;
  floatx4* ov = (floatx4*)out;
  int base = c * CH * L4 + col4;

  int o = c * L4 + col4;
  floatx4 m4 = ((const floatx4*)Ms)[o];
  floatx4 v4 = ((const floatx4*)Vs)[o];
  float mu[4] = {m4[0], m4[1], m4[2], m4[3]};
  float vv[4] = {v4[0], v4[1], v4[2], v4[3]};
#pragma unroll 4
  for (int i = 0; i < CH; ++i) {
    floatx4 v = xv[base + i * L4];
    floatx4 oe;
#pragma unroll
    for (int k = 0; k < 4; ++k) {
      float d = v[k] - mu[k];
      oe[k] = d * rsqrtf(vv[k] + EPSV);
      vv[k] = fmaf(AFWD, vv[k], KCOEF * (d * d));
      mu[k] = fmaf(ONE_MINUS_A, d, mu[k]);
    }
    __builtin_nontemporal_store(oe, &ov[base + i * L4]);
  }
}

extern "C" void kernel_launch(void* const* d_in, const int* in_sizes, int n_in,
                              void* d_out, int out_size, void* d_ws, size_t ws_size,
                              hipStream_t stream) {
  const float* x   = (const float*)d_in[0];
  const float* m   = (const float*)d_in[1];
  const float* var = (const float*)d_in[2];
  float* out = (float*)d_out;

  int L  = in_sizes[1];          // 4096
  int N  = in_sizes[0] / L;      // 8192
  int L4 = L / 4;

  // C=128 -> 512 blocks (coop-safe even at 2 blocks/CU); CH=64.
  int C = 128;
  while (C > 1 &&
         ((size_t)(5 * C + 5 * (C / 16 + 1)) * L * sizeof(float) > ws_size ||
          (N % C) != 0 || ((N / C) % 4) != 0))
    C >>= 1;
  int CH = N / C;
  int SUB = (C >= 16) ? 16 : C;
  int GS  = C / SUB;

  double a = 0.999;
  float A    = (float)pow(a, (double)CH);
  float c_eg = (float)pow(a, (double)(CH - 1));
  float Sgg  = (float)(pow(a, (double)(CH - 1)) * (1.0 - pow(a, (double)CH)) / (1.0 - a));
  float G    = (float)((1.0 - pow(a, (double)CH)) / (1.0 - a));
  double nS = (double)SUB * CH;
  float Asup   = (float)pow(a, nS);
  float c_sup  = (float)pow(a, nS - 1.0);
  float Sggsup = (float)(pow(a, nS - 1.0) * (1.0 - pow(a, nS)) / (1.0 - a));

  float* ws  = (float*)d_ws;
  size_t CL  = (size_t)C * L;
  size_t GL  = (size_t)GS * L;
  float* Bmu  = ws;
  float* See  = ws + CL;
  float* Te   = ws + 2 * CL;
  float* Ms   = ws + 3 * CL;
  float* Vs   = ws + 4 * CL;
  float* Bsup = ws + 5 * CL;
  float* Ssup = Bsup + GL;
  float* Tsup = Bsup + 2 * GL;
  float* Mg   = Bsup + 3 * GL;
  float* Vg   = Bsup + 4 * GL;

  int threadsBig = C * L4;
  int gridBlocks = threadsBig / 256;

  // Host-side occupancy guard (graph-capture-safe queries): take the coop
  // path only if the whole grid is co-resident.
  int dev = 0, numCU = 0, maxPerCU = 0;
  hipGetDevice(&dev);
  hipDeviceGetAttribute(&numCU, hipDeviceAttributeMultiprocessorCount, dev);
  hipOccupancyMaxActiveBlocksPerMultiprocessor(&maxPerCU, fused_cn3, 256, 0);
  bool coop_ok = (maxPerCU > 0 && numCU > 0 &&
                  (long)maxPerCU * numCU >= gridBlocks);

  if (coop_ok) {
    dim3 grid(gridBlocks), block(256);
    void* args[] = {(void*)&x,    (void*)&m,    (void*)&var,  (void*)&out,
                    (void*)&Bmu,  (void*)&See,  (void*)&Te,   (void*)&Ms,
                    (void*)&Vs,   (void*)&Bsup, (void*)&Ssup, (void*)&Tsup,
                    (void*)&Mg,   (void*)&Vg,   (void*)&L,    (void*)&L4,
                    (void*)&C,    (void*)&CH,   (void*)&SUB,  (void*)&GS,
                    (void*)&A,    (void*)&c_eg, (void*)&Sgg,  (void*)&G,
                    (void*)&Asup, (void*)&c_sup, (void*)&Sggsup};
    hipError_t err = hipLaunchCooperativeKernel((const void*)fused_cn3, grid,
                                                block, args, 0, stream);
    if (err == hipSuccess) return;
  }

  // Fallback: proven 5-kernel path.
  passA<<<gridBlocks, 256, 0, stream>>>(x, Bmu, See, Te, L4, CH);
  passB1<<<(L * GS) / 256, 256, 0, stream>>>(Bmu, See, Te, Bsup, Ssup, Tsup,
                                             L, SUB, A, c_eg, Sgg, G);
  passB2<<<L / 256, 256, 0, stream>>>(m, var, Bsup, Ssup, Tsup, Mg, Vg, L, GS,
                                      Asup, c_sup, Sggsup);
  passB3<<<(L * GS) / 256, 256, 0, stream>>>(Bmu, See, Te, Mg, Vg, Ms, Vs,
                                             L, SUB, A, c_eg, Sgg);
  passC<<<gridBlocks, 256, 0, stream>>>(x, Ms, Vs, out, L4, CH);
}

// Round 10
// 74.542 us; speedup vs baseline: 4.0259x; 4.0259x over previous
//
#include <hip/hip_runtime.h>
#include <math.h>

#define AFWD 0.999f
#define ONE_MINUS_A (1.0f - 0.999f)
#define KCOEF (0.999f * (1.0f - 0.999f))
#define EPSV 1e-5f

typedef float floatx4 __attribute__((ext_vector_type(4)));

// ---------------------------------------------------------------------------
// Pass A: per (chunk c, col4) local summaries with chunk-start M=0.
//   Bmu = local mu after CH steps, Te = sum e_i, See = sum a^{CH-1-i} e_i^2
// ---------------------------------------------------------------------------
__global__ __launch_bounds__(256) void
passA(const float* __restrict__ x, float* __restrict__ Bmu,
      float* __restrict__ See, float* __restrict__ Te, int L4, int CH) {
  int idx  = blockIdx.x * blockDim.x + threadIdx.x;
  int col4 = idx % L4;
  int c    = idx / L4;
  const floatx4* xv = (const floatx4*)x;
  int base = c * CH * L4 + col4;

  float mu[4] = {0.f, 0.f, 0.f, 0.f};
  float s[4]  = {0.f, 0.f, 0.f, 0.f};
  float t[4]  = {0.f, 0.f, 0.f, 0.f};
#pragma unroll 4
  for (int i = 0; i < CH; ++i) {
    floatx4 v = xv[base + i * L4];
#pragma unroll
    for (int k = 0; k < 4; ++k) {
      float e = v[k] - mu[k];
      s[k] = fmaf(AFWD, s[k], e * e);
      t[k] += e;
      mu[k] = fmaf(ONE_MINUS_A, e, mu[k]);
    }
  }
  int o = c * L4 + col4;
  floatx4 om = {mu[0], mu[1], mu[2], mu[3]};
  floatx4 os = {s[0], s[1], s[2], s[3]};
  floatx4 ot = {t[0], t[1], t[2], t[3]};
  ((floatx4*)Bmu)[o] = om;
  ((floatx4*)See)[o] = os;
  ((floatx4*)Te)[o]  = ot;
}

// ---------------------------------------------------------------------------
// Pass B (single kernel, block-local): block = 8 super-chunk slots x 32 cols.
// Stage 1: thread (g,lc) composes SUB chunk summaries -> LDS.
// Stage 2: 32 threads walk the GS super-chunks in LDS with (M0,V0).
// Stage 3: thread (g,lc) emits its SUB chunk-start states (Ms,Vs).
// Composition algebra (proven R6):
//   S <- A*S + s2 - 2*c_eg*B*t2 + Sgg*B^2 ;  T <- T + t2 - G*B ;  B <- A*B+b2
// ---------------------------------------------------------------------------
__global__ __launch_bounds__(256) void
passBfused(const float* __restrict__ m, const float* __restrict__ var,
           const float* __restrict__ Bmu, const float* __restrict__ See,
           const float* __restrict__ Te, float* __restrict__ Ms,
           float* __restrict__ Vs, int L, int SUB, int GS,
           float A, float c_eg, float Sgg, float G,
           float Asup, float c_sup, float Sggsup) {
  __shared__ float Bs[8][32], Ss[8][32], Ts[8][32];
  __shared__ float MgL[8][32], VgL[8][32];

  int g  = threadIdx.x >> 5;
  int lc = threadIdx.x & 31;
  int l  = blockIdx.x * 32 + lc;

  // ---- stage 1: super-chunk summaries ----
  {
    int base = g * SUB * L + l;
    float B = 0.f, T = 0.f, S = 0.f;
#pragma unroll 4
    for (int k = 0; k < SUB; ++k) {
      int o = base + k * L;
      float b2 = Bmu[o];
      float s2 = See[o];
      float t2 = Te[o];
      S = fmaf(A, S, fmaf(Sgg * B, B, fmaf(-2.0f * c_eg * B, t2, s2)));
      T = fmaf(-G, B, T + t2);
      B = fmaf(A, B, b2);
    }
    Bs[g][lc] = B;
    Ss[g][lc] = S;
    Ts[g][lc] = T;
  }

  __syncthreads();

  // ---- stage 2: walk super-chunks (32 threads) ----
  if (threadIdx.x < 32) {
    float M = m[l];
    float V = var[l];
#pragma unroll
    for (int gg = 0; gg < 8; ++gg) {
      if (gg >= GS) break;
      MgL[gg][lc] = M;
      VgL[gg][lc] = V;
      float b = Bs[gg][lc];
      float s = Ss[gg][lc];
      float t = Ts[gg][lc];
      float sum = fmaf(M * M, Sggsup, fmaf(-2.0f * c_sup * M, t, s));
      V = fmaf(Asup, V, KCOEF * sum);
      M = fmaf(Asup, M, b);
    }
  }

  __syncthreads();

  // ---- stage 3: emit chunk-start states ----
  {
    float M = MgL[g][lc];
    float V = VgL[g][lc];
    int base = g * SUB * L + l;
#pragma unroll 4
    for (int k = 0; k < SUB; ++k) {
      int o = base + k * L;
      Ms[o] = M;
      Vs[o] = V;
      float b = Bmu[o];
      float s = See[o];
      float t = Te[o];
      float sum = fmaf(M * M, Sgg, fmaf(-2.0f * c_eg * M, t, s));
      V = fmaf(A, V, KCOEF * sum);
      M = fmaf(A, M, b);
    }
  }
}

// ---------------------------------------------------------------------------
// Pass C: replay exact recurrence from (M_c, V_c). NT out stores keep x
// L3-resident (R9's coop run proved L3 absorbs the re-read: FETCH=136MB).
// ---------------------------------------------------------------------------
__global__ __launch_bounds__(256) void
passC(const float* __restrict__ x, const float* __restrict__ Ms,
      const float* __restrict__ Vs, float* __restrict__ out, int L4, int CH) {
  int idx  = blockIdx.x * blockDim.x + threadIdx.x;
  int col4 = idx % L4;
  int c    = idx / L4;
  const floatx4* xv = (const floatx4*)x;
  floatx4* ov = (floatx4*)out;
  int base = c * CH * L4 + col4;

  int o = c * L4 + col4;
  floatx4 m4 = ((const floatx4*)Ms)[o];
  floatx4 v4 = ((const floatx4*)Vs)[o];
  float mu[4] = {m4[0], m4[1], m4[2], m4[3]};
  float vv[4] = {v4[0], v4[1], v4[2], v4[3]};
#pragma unroll 4
  for (int i = 0; i < CH; ++i) {
    floatx4 v = xv[base + i * L4];
    floatx4 oe;
#pragma unroll
    for (int k = 0; k < 4; ++k) {
      float d = v[k] - mu[k];
      oe[k] = d * rsqrtf(vv[k] + EPSV);
      vv[k] = fmaf(AFWD, vv[k], KCOEF * (d * d));
      mu[k] = fmaf(ONE_MINUS_A, d, mu[k]);
    }
    __builtin_nontemporal_store(oe, &ov[base + i * L4]);
  }
}

extern "C" void kernel_launch(void* const* d_in, const int* in_sizes, int n_in,
                              void* d_out, int out_size, void* d_ws, size_t ws_size,
                              hipStream_t stream) {
  const float* x   = (const float*)d_in[0];
  const float* m   = (const float*)d_in[1];
  const float* var = (const float*)d_in[2];
  float* out = (float*)d_out;

  int L  = in_sizes[1];          // 4096
  int N  = in_sizes[0] / L;      // 8192
  int L4 = L / 4;

  // C=128 chunks (proven), CH=64; SUB=16 chunks/super-chunk, GS=8.
  int C = 128;
  while (C > 1 &&
         ((size_t)5 * C * L * sizeof(float) > ws_size || (N % C) != 0))
    C >>= 1;
  int CH = N / C;
  int SUB = (C >= 16) ? 16 : C;
  int GS  = C / SUB;   // must be <= 8 for passBfused's LDS arrays

  double a = 0.999;
  float A    = (float)pow(a, (double)CH);
  float c_eg = (float)pow(a, (double)(CH - 1));
  float Sgg  = (float)(pow(a, (double)(CH - 1)) * (1.0 - pow(a, (double)CH)) / (1.0 - a));
  float G    = (float)((1.0 - pow(a, (double)CH)) / (1.0 - a));
  double nS = (double)SUB * CH;
  float Asup   = (float)pow(a, nS);
  float c_sup  = (float)pow(a, nS - 1.0);
  float Sggsup = (float)(pow(a, nS - 1.0) * (1.0 - pow(a, nS)) / (1.0 - a));

  float* ws  = (float*)d_ws;
  size_t CL  = (size_t)C * L;
  float* Bmu  = ws;
  float* See  = ws + CL;
  float* Te   = ws + 2 * CL;
  float* Ms   = ws + 3 * CL;
  float* Vs   = ws + 4 * CL;

  int gridBlocks = (C * L4) / 256;
  passA<<<gridBlocks, 256, 0, stream>>>(x, Bmu, See, Te, L4, CH);
  passBfused<<<L / 32, 256, 0, stream>>>(m, var, Bmu, See, Te, Ms, Vs, L,
                                         SUB, GS, A, c_eg, Sgg, G,
                                         Asup, c_sup, Sggsup);
  passC<<<gridBlocks, 256, 0, stream>>>(x, Ms, Vs, out, L4, CH);
}